// Round 3
// baseline (247.668 us; speedup 1.0000x reference)
//
#include <hip/hip_runtime.h>
#include <hip/hip_bf16.h>

// B=32, S=1024, C=D=512 attention, fp32 in/out.
//   1. convert: x -> bf16; [Wq*scale | Wk | Wv] -> bf16 (contiguous 1536x512)
//   2. gemm_dp<QKV>: [Q|K|V] = X W'^T, M=32768 N=1536 K=512
//   3. gemm_dp<BF16>: S = Q K^T per batch
//   4. softmax_rows
//   5. gemm_dp<F32>: out = P V  (B operand = V^T)
//
// gemm_dp: 256x256 tile, BK=32, 8 waves (2Mx4N), 4-deep LDS K-tile ring
// (4 x 32KB = 128 KiB), prefetch 3 K-tiles ahead, ONE vmcnt(6) per K-tile
// (drain lag 3-4 phases > HBM latency), register-frag pipelining one phase
// ahead with counted lgkmcnt, 1 barrier per phase, setprio around MFMA,
// XOR-swizzled LDS (slot ^= (row>>1)&3) staged via pre-swizzled global src.

typedef __attribute__((ext_vector_type(8))) short short8;
typedef __attribute__((ext_vector_type(4))) float f32x4;

#define GLD16(g, l)                                                         \
  __builtin_amdgcn_global_load_lds(                                         \
      (const __attribute__((address_space(1))) void*)(g),                   \
      (__attribute__((address_space(3))) void*)(l), 16, 0, 0)

__device__ __forceinline__ unsigned short f2bf(float f) {
  unsigned int u = __float_as_uint(f);
  u += 0x7fffu + ((u >> 16) & 1u);  // round-to-nearest-even
  return (unsigned short)(u >> 16);
}

enum { ST_QKV = 0, ST_BF16 = 1, ST_F32 = 2 };

// C = A * B^T, A [M x K] row-major (lda), B [N x K] row-major (ldb), bf16.
// Grid: x = M/256, y = N/256, z = batch.
template <int STORE>
__global__ __launch_bounds__(512, 2) void gemm_dp(
    const unsigned short* __restrict__ A, const unsigned short* __restrict__ B,
    void* __restrict__ Cout, int K, int lda, int ldb, int ldc, long aS,
    long bS, long cS, unsigned short* __restrict__ qd,
    unsigned short* __restrict__ kd, unsigned short* __restrict__ vd) {
  // 4 ring buffers; each: A-tile [256x32] (16KB) then B-tile [256x32] (16KB).
  __shared__ char lds[131072];

  const int tid = threadIdx.x;
  const int lane = tid & 63;
  const int l15 = lane & 15;
  const int g = lane >> 4;
  const int wid = tid >> 6;
  const int wm = wid >> 2;  // 0..1
  const int wn = wid & 3;   // 0..3

  const unsigned short* Ag =
      A + (long)blockIdx.z * aS + (long)(blockIdx.x * 256) * lda;
  const unsigned short* Bg =
      B + (long)blockIdx.z * bS + (long)(blockIdx.y * 256) * ldb;

  const int NT = K >> 5;  // K-tiles of 32

  f32x4 acc[8][4];
#pragma unroll
  for (int i = 0; i < 8; ++i)
#pragma unroll
    for (int j = 0; j < 4; ++j) acc[i][j] = (f32x4)(0.0f);

  // ---- staging: one operand K-tile = 2 gld_lds ops/thread.
  // LDS chunk c (16B) at row r=c>>2, slot c&3 holds global slot (c&3)^((r>>1)&3)
  // => LDS layout byte(r, s*16) = data of K-chunk s^((r>>1)&3): bank-spread,
  // gld_lds dest stays linear (wave-uniform base + lane*16).
  auto stageA = [&](int u) {
    int uc = (u < NT) ? u : (NT - 1);  // address clamp; buffer u&3 dead if u>=NT
    char* dst = lds + ((u & 3) << 15);
#pragma unroll
    for (int o = 0; o < 2; ++o) {
      int c = (o << 9) | tid;
      int r = c >> 2;
      int sl = (c & 3) ^ ((r >> 1) & 3);
      GLD16(Ag + (long)r * lda + (uc << 5) + (sl << 3), dst + (c << 4));
    }
  };
  auto stageB = [&](int u) {
    int uc = (u < NT) ? u : (NT - 1);
    char* dst = lds + ((u & 3) << 15) + 16384;
#pragma unroll
    for (int o = 0; o < 2; ++o) {
      int c = (o << 9) | tid;
      int r = c >> 2;
      int sl = (c & 3) ^ ((r >> 1) & 3);
      GLD16(Bg + (long)r * ldb + (uc << 5) + (sl << 3), dst + (c << 4));
    }
  };

  // ---- frag reads (per-lane swizzled ds_read_b128); row offsets fixed per
  // mi/nj so the compiler CSEs the address math outside the loop.
  auto ldsA = [&](int u, int mi) {
    const char* base = lds + ((u & 3) << 15);
    int row = ((mi * 2 + wm) << 4) + l15;
    return *(const short8*)(base + row * 64 +
                            ((g << 4) ^ (((row >> 1) & 3) << 4)));
  };
  auto ldsB = [&](int u, int nj) {
    const char* base = lds + ((u & 3) << 15) + 16384;
    int row = ((nj * 4 + wn) << 4) + l15;
    return *(const short8*)(base + row * 64 +
                            ((g << 4) ^ (((row >> 1) & 3) << 4)));
  };

  // ---- prologue: stage tiles 0,1,2 (12 ops); tile 0 resident after vmcnt(8).
  stageA(0); stageB(0);
  stageA(1); stageB(1);
  stageA(2); stageB(2);
  asm volatile("s_waitcnt vmcnt(8)" ::: "memory");
  __builtin_amdgcn_s_barrier();

  short8 afA[8], afB[8], b01A[2], b01B[2], b23[2];
#pragma unroll
  for (int m = 0; m < 8; ++m) afA[m] = ldsA(0, m);
  b01A[0] = ldsB(0, 0);
  b01A[1] = ldsB(0, 1);

  // Per K-tile: ph1 {read bf23(t); stage A(t+3); lgkm(2); MFMA njL; vmcnt(6);
  // bar} ph2 {read af/b01(t+1); stage B(t+3); lgkm(10); MFMA njH; bar}.
  // vmcnt(6) ledger: newest 6 ops = A(t+3),B(t+2),A(t+2) => A,B(t+1) landed
  // before ph2 reads buf(t+1). Drain lag 3-4 phases (~1500cy) > HBM ~900cy.
  auto tile = [&](int t, short8(&afc)[8], short8(&b01c)[2], short8(&afn)[8],
                  short8(&b01n)[2]) {
    // ---- phase 1
    b23[0] = ldsB(t, 2);
    b23[1] = ldsB(t, 3);
    stageA(t + 3);
    asm volatile("s_waitcnt lgkmcnt(2)" ::: "memory");  // afc,b01c ready
    __builtin_amdgcn_sched_barrier(0);
    __builtin_amdgcn_s_setprio(1);
#pragma unroll
    for (int m = 0; m < 8; ++m)
#pragma unroll
      for (int n = 0; n < 2; ++n)
        acc[m][n] = __builtin_amdgcn_mfma_f32_16x16x32_bf16(afc[m], b01c[n],
                                                            acc[m][n], 0, 0, 0);
    __builtin_amdgcn_s_setprio(0);
    __builtin_amdgcn_sched_barrier(0);
    asm volatile("s_waitcnt vmcnt(6)" ::: "memory");
    __builtin_amdgcn_s_barrier();
    // ---- phase 2
#pragma unroll
    for (int m = 0; m < 8; ++m) afn[m] = ldsA(t + 1, m);
    b01n[0] = ldsB(t + 1, 0);
    b01n[1] = ldsB(t + 1, 1);
    stageB(t + 3);
    asm volatile("s_waitcnt lgkmcnt(10)" ::: "memory");  // b23 ready
    __builtin_amdgcn_sched_barrier(0);
    __builtin_amdgcn_s_setprio(1);
#pragma unroll
    for (int m = 0; m < 8; ++m)
#pragma unroll
      for (int n = 0; n < 2; ++n)
        acc[m][2 + n] = __builtin_amdgcn_mfma_f32_16x16x32_bf16(
            afc[m], b23[n], acc[m][2 + n], 0, 0, 0);
    __builtin_amdgcn_s_setprio(0);
    __builtin_amdgcn_sched_barrier(0);
    __builtin_amdgcn_s_barrier();
  };

  for (int t = 0; t < NT; t += 2) {  // NT is even (16 or 32)
    tile(t, afA, b01A, afB, b01B);
    tile(t + 1, afB, b01B, afA, b01A);
  }

  // ---- epilogue. C/D frag layout: col = l15, row = g*4 + r (m89-verified).
  const int rbase = blockIdx.x * 256;
  const int cbase = blockIdx.y * 256;

  if (STORE == ST_F32) {
    float* C = (float*)Cout + (long)blockIdx.z * cS;
#pragma unroll
    for (int mi = 0; mi < 8; ++mi)
#pragma unroll
      for (int nj = 0; nj < 4; ++nj)
#pragma unroll
        for (int r = 0; r < 4; ++r) {
          int row = rbase + ((mi * 2 + wm) << 4) + (g << 2) + r;
          int col = cbase + ((nj * 4 + wn) << 4) + l15;
          C[(long)row * ldc + col] = acc[mi][nj][r];
        }
  } else if (STORE == ST_BF16) {
    unsigned short* C = (unsigned short*)Cout + (long)blockIdx.z * cS;
#pragma unroll
    for (int mi = 0; mi < 8; ++mi)
#pragma unroll
      for (int nj = 0; nj < 4; ++nj)
#pragma unroll
        for (int r = 0; r < 4; ++r) {
          int row = rbase + ((mi * 2 + wm) << 4) + (g << 2) + r;
          int col = cbase + ((nj * 4 + wn) << 4) + l15;
          C[(long)row * ldc + col] = f2bf(acc[mi][nj][r]);
        }
  } else {  // ST_QKV: by 0,1 -> Q; 2,3 -> K; 4,5 -> V^T [b][d][s]
    const int widx = blockIdx.y >> 1;
    unsigned short* dst = (widx == 0) ? qd : ((widx == 1) ? kd : vd);
#pragma unroll
    for (int mi = 0; mi < 8; ++mi)
#pragma unroll
      for (int nj = 0; nj < 4; ++nj)
#pragma unroll
        for (int r = 0; r < 4; ++r) {
          int row = rbase + ((mi * 2 + wm) << 4) + (g << 2) + r;  // b*1024+s
          int col = ((blockIdx.y & 1) << 8) + ((nj * 4 + wn) << 4) + l15;
          unsigned short v = f2bf(acc[mi][nj][r]);
          if (widx < 2)
            dst[(long)row * 512 + col] = v;
          else
            dst[(long)(row >> 10) * 524288 + (long)col * 1024 + (row & 1023)] =
                v;
        }
  }
}

// In-place row softmax over 32768 rows of 1024 bf16. One wave per row.
__global__ __launch_bounds__(256) void softmax_rows(
    unsigned short* __restrict__ S) {
  const long row = (long)blockIdx.x * 4 + (threadIdx.x >> 6);
  const int lane = threadIdx.x & 63;
  unsigned short* p = S + row * 1024 + lane * 16;
  uint4 u0 = *(const uint4*)p;
  uint4 u1 = *(const uint4*)(p + 8);
  unsigned int us[8] = {u0.x, u0.y, u0.z, u0.w, u1.x, u1.y, u1.z, u1.w};
  float v[16];
#pragma unroll
  for (int j = 0; j < 8; ++j) {
    v[2 * j] = __uint_as_float(us[j] << 16);
    v[2 * j + 1] = __uint_as_float(us[j] & 0xffff0000u);
  }
  float m = v[0];
#pragma unroll
  for (int i = 1; i < 16; ++i) m = fmaxf(m, v[i]);
#pragma unroll
  for (int off = 32; off >= 1; off >>= 1) m = fmaxf(m, __shfl_xor(m, off, 64));
  float s = 0.0f;
#pragma unroll
  for (int i = 0; i < 16; ++i) {
    v[i] = __expf(v[i] - m);
    s += v[i];
  }
#pragma unroll
  for (int off = 32; off >= 1; off >>= 1) s += __shfl_xor(s, off, 64);
  const float inv = 1.0f / s;
#pragma unroll
  for (int j = 0; j < 8; ++j) {
    unsigned int lo = f2bf(v[2 * j] * inv);
    unsigned int hi = f2bf(v[2 * j + 1] * inv);
    us[j] = lo | (hi << 16);
  }
  uint4 o0 = {us[0], us[1], us[2], us[3]};
  uint4 o1 = {us[4], us[5], us[6], us[7]};
  *(uint4*)p = o0;
  *(uint4*)(p + 8) = o1;
}

// Convert x and the three 512x512 weights to bf16 (Wq pre-scaled by 1/sqrt(512)).
__global__ __launch_bounds__(256) void convert_in(
    const float* __restrict__ x, const float* __restrict__ wq,
    const float* __restrict__ wk, const float* __restrict__ wv,
    unsigned short* __restrict__ xb, unsigned short* __restrict__ wb) {
  const long i = (long)blockIdx.x * 256 + threadIdx.x;
  const long NX4 = 16777216 / 4;
  const float* src;
  unsigned short* dst;
  long off;
  float sc = 1.0f;
  if (i < NX4) {
    src = x;
    dst = xb;
    off = i;
  } else {
    long r = i - NX4;
    int w = (int)(r >> 16);
    off = r & 65535;
    src = (w == 0) ? wq : (w == 1) ? wk : wv;
    dst = wb + (long)w * 262144;
    if (w == 0) sc = 0.044194173824159216f;  // 1/sqrt(512)
  }
  float4 f = ((const float4*)src)[off];
  ushort4 o;
  o.x = f2bf(f.x * sc);
  o.y = f2bf(f.y * sc);
  o.z = f2bf(f.z * sc);
  o.w = f2bf(f.w * sc);
  ((ushort4*)dst)[off] = o;
}

extern "C" void kernel_launch(void* const* d_in, const int* in_sizes, int n_in,
                              void* d_out, int out_size, void* d_ws,
                              size_t ws_size, hipStream_t stream) {
  const float* x = (const float*)d_in[0];
  const float* wq = (const float*)d_in[1];
  const float* wk = (const float*)d_in[2];
  const float* wv = (const float*)d_in[3];
  float* out = (float*)d_out;

  unsigned short* xb = (unsigned short*)d_ws;  // 16777216
  unsigned short* wb = xb + 16777216;          // 3*262144 (wq_s|wk|wv)
  unsigned short* qb = wb + 786432;            // 16777216
  unsigned short* kb = qb + 16777216;          // 16777216
  unsigned short* vtb = kb + 16777216;         // 16777216 (V^T [b][d][s])
  unsigned short* sb = vtb + 16777216;         // 33554432 (S -> P in place)

  convert_in<<<17152, 256, 0, stream>>>(x, wq, wk, wv, xb, wb);

  // QKV: M=32768, N=1536, K=512
  gemm_dp<ST_QKV><<<dim3(128, 6, 1), 512, 0, stream>>>(
      xb, wb, nullptr, 512, 512, 512, 0, 0L, 0L, 0L, qb, kb, vtb);

  // S = Q K^T per batch: M=N=1024, K=512
  gemm_dp<ST_BF16><<<dim3(4, 4, 32), 512, 0, stream>>>(
      qb, kb, sb, 512, 512, 512, 1024, 524288L, 524288L, 1048576L, nullptr,
      nullptr, nullptr);

  softmax_rows<<<8192, 256, 0, stream>>>(sb);

  // out = P V: M=1024, N=512, K=1024
  gemm_dp<ST_F32><<<dim3(4, 2, 32), 512, 0, stream>>>(
      sb, vtb, out, 1024, 1024, 1024, 512, 1048576L, 524288L, 524288L, nullptr,
      nullptr, nullptr);
}

// Round 4
// 233.696 us; speedup vs baseline: 1.0598x; 1.0598x over previous
//
#include <hip/hip_runtime.h>
#include <hip/hip_bf16.h>

// B=32, S=1024, C=D=512 attention, fp32 in/out.
//   1. convert: x -> bf16; [Wq*scale | Wk | Wv] -> bf16 (contiguous 1536x512)
//   2. gemm8p<QKV,0>:  [Q|K|V] = X W'^T, M=32768 N=1536 K=512
//   3. gemm8p<BF16,1>: S = Q K^T per batch
//   4. softmax_rows
//   5. gemm8p<F32,2>:  out = P V  (B operand = V^T)
//
// gemm8p: 256x256 tile, BK=64, 8 waves, 128 KiB LDS dbuf, 4 quadrant-phases
// per K-tile, counted vmcnt(4), XOR-swizzled LDS via pre-swizzled global src.
//
// NEW (round 4): XCD-supertile block swizzle. HW round-robins linear block id
// across 8 XCDs (id%8). We decode ids so each XCD works on a supertile whose
// operand panels fit its private 4 MiB L2:
//   SWZ=0 (QKV): supertile = 8 x-tiles x 6 y-tiles (A 2MB + B 1.5MB resident)
//   SWZ=1 (S):   supertile = one batch (16 blocks; Q+K = 2MB resident)
//   SWZ=2 (PV):  supertile = one batch (8 blocks; P 2MB + V 1MB)

typedef __attribute__((ext_vector_type(8))) short short8;
typedef __attribute__((ext_vector_type(4))) float f32x4;

#define GLD16(g, l)                                                         \
  __builtin_amdgcn_global_load_lds(                                         \
      (const __attribute__((address_space(1))) void*)(g),                   \
      (__attribute__((address_space(3))) void*)(l), 16, 0, 0)

__device__ __forceinline__ unsigned short f2bf(float f) {
  unsigned int u = __float_as_uint(f);
  u += 0x7fffu + ((u >> 16) & 1u);  // round-to-nearest-even
  return (unsigned short)(u >> 16);
}

enum { ST_QKV = 0, ST_BF16 = 1, ST_F32 = 2 };

#define PH_SYNC                                                             \
  asm volatile("s_waitcnt vmcnt(4)" ::: "memory");                          \
  __builtin_amdgcn_s_barrier();                                             \
  asm volatile("s_waitcnt lgkmcnt(0)" ::: "memory");                        \
  __builtin_amdgcn_sched_barrier(0);                                        \
  __builtin_amdgcn_s_setprio(1);

#define PH_END                                                              \
  __builtin_amdgcn_s_setprio(0);                                            \
  __builtin_amdgcn_s_barrier();

// C = A * B^T, A [M x K] row-major (lda), B [N x K] row-major (ldb), bf16 in.
// 1-D grid; block coords decoded per SWZ (bijective XCD-supertile mappings).
template <int STORE, int SWZ>
__global__ __launch_bounds__(512, 2) void gemm8p(
    const unsigned short* __restrict__ A, const unsigned short* __restrict__ B,
    void* __restrict__ Cout, int K, int lda, int ldb, int ldc, long aS,
    long bS, long cS, unsigned short* __restrict__ qd,
    unsigned short* __restrict__ kd, unsigned short* __restrict__ vd) {
  __shared__ unsigned short As[2][16384];
  __shared__ unsigned short Bs[2][16384];

  int bx, by, bz;
  {
    const int i = blockIdx.x;
    const int x0 = i & 7;      // XCD (hw: linear id % 8)
    const int j = i >> 3;      // position within this XCD's sequence
    if (SWZ == 0) {            // grid 768: 16 supertiles of 8x-tiles x 6y
      const int s2 = j / 48;   // which supertile round (0..1)
      const int p = j - s2 * 48;
      const int s = x0 + (s2 << 3);  // supertile 0..15
      bx = (s << 3) + (p & 7);       // 0..127
      by = p >> 3;                   // 0..5
      bz = 0;
    } else if (SWZ == 1) {     // grid 512: batch=16 blocks (4x4)
      const int s2 = j >> 4;   // 0..3
      const int p = j & 15;
      bz = x0 + (s2 << 3);     // 0..31
      bx = p & 3;
      by = p >> 2;
    } else {                   // grid 256: batch=8 blocks (4x2)
      const int s2 = j >> 3;   // 0..3
      const int p = j & 7;
      bz = x0 + (s2 << 3);     // 0..31
      bx = p & 3;
      by = p >> 1 == 0 ? 0 : 1;
      by = p >> 2;             // 0..1
    }
  }

  const int tid = threadIdx.x;
  const int lane = tid & 63;
  const int l15 = lane & 15;
  const int g = lane >> 4;
  const int wid = tid >> 6;
  const int wm = wid >> 2;  // 0..1
  const int wn = wid & 3;   // 0..3
  const int xorv = (l15 & 7) << 4;

  const unsigned short* Ag = A + (long)bz * aS + (long)(bx * 256) * lda;
  const unsigned short* Bg = B + (long)bz * bS + (long)(by * 256) * ldb;

  char* Ab = (char*)&As[0][0];
  char* Bb = (char*)&Bs[0][0];

  f32x4 acc[8][4];
#pragma unroll
  for (int i = 0; i < 8; ++i)
#pragma unroll
    for (int j = 0; j < 4; ++j) acc[i][j] = (f32x4)(0.0f);

  // stage one half-tile (128 rows x 64 cols bf16 = 16 KB) of A or B.
  auto stage = [&](const unsigned short* G, int ld, int half, int k0,
                   char* dst) {
#pragma unroll
    for (int j = 0; j < 2; ++j) {
      int c = (j << 9) | tid;  // 0..1023 16B chunks
      int r = c >> 3;          // 0..127
      int cc = c & 7;
      int sc = cc ^ (r & 7);
      GLD16(G + (long)((half << 7) + r) * ld + k0 + (sc << 3),
            dst + (half << 14) + (c << 4));
    }
  };

  auto ldA = [&](const char* base, int mi, int ks) {
    int row = ((mi * 2 + wm) << 4) + l15;
    return *(const short8*)(base + row * 128 +
                            (((g << 4) + (ks << 6)) ^ xorv));
  };
  auto ldB = [&](const char* base, int nj, int ks) {
    int row = ((nj * 4 + wn) << 4) + l15;
    return *(const short8*)(base + row * 128 +
                            (((g << 4) + (ks << 6)) ^ xorv));
  };

  const int NT = K >> 6;

  stage(Ag, lda, 0, 0, Ab);
  stage(Bg, ldb, 0, 0, Bb);
  stage(Bg, ldb, 1, 0, Bb);
  stage(Ag, lda, 1, 0, Ab);
  asm volatile("s_waitcnt vmcnt(4)" ::: "memory");
  __builtin_amdgcn_s_barrier();

  for (int t = 0; t < NT; ++t) {
    const char* Ac = Ab + ((t & 1) << 15);
    const char* Bc = Bb + ((t & 1) << 15);
    char* An = Ab + (((t + 1) & 1) << 15);
    char* Bn = Bb + (((t + 1) & 1) << 15);
    const int k1 = (t + 1) << 6;
    const bool st = (t + 1) < NT;
    short8 af[4][2], bfL[2][2], bfH[2][2];

    // ---- phase 1: quadrant (mih=0, njh=0) ----
#pragma unroll
    for (int m = 0; m < 4; ++m) {
      af[m][0] = ldA(Ac, m, 0);
      af[m][1] = ldA(Ac, m, 1);
    }
#pragma unroll
    for (int n = 0; n < 2; ++n) {
      bfL[n][0] = ldB(Bc, n, 0);
      bfL[n][1] = ldB(Bc, n, 1);
    }
    if (st) stage(Ag, lda, 0, k1, An);
    PH_SYNC
#pragma unroll
    for (int m = 0; m < 4; ++m)
#pragma unroll
      for (int n = 0; n < 2; ++n)
#pragma unroll
        for (int ks = 0; ks < 2; ++ks)
          acc[m][n] = __builtin_amdgcn_mfma_f32_16x16x32_bf16(
              af[m][ks], bfL[n][ks], acc[m][n], 0, 0, 0);
    PH_END

    // ---- phase 2: quadrant (mih=0, njh=1) ----
#pragma unroll
    for (int n = 0; n < 2; ++n) {
      bfH[n][0] = ldB(Bc, 2 + n, 0);
      bfH[n][1] = ldB(Bc, 2 + n, 1);
    }
    if (st) stage(Bg, ldb, 0, k1, Bn);
    PH_SYNC
#pragma unroll
    for (int m = 0; m < 4; ++m)
#pragma unroll
      for (int n = 0; n < 2; ++n)
#pragma unroll
        for (int ks = 0; ks < 2; ++ks)
          acc[m][2 + n] = __builtin_amdgcn_mfma_f32_16x16x32_bf16(
              af[m][ks], bfH[n][ks], acc[m][2 + n], 0, 0, 0);
    PH_END

    // ---- phase 3: quadrant (mih=1, njh=0) ----
#pragma unroll
    for (int m = 0; m < 4; ++m) {
      af[m][0] = ldA(Ac, 4 + m, 0);
      af[m][1] = ldA(Ac, 4 + m, 1);
    }
    if (st) stage(Bg, ldb, 1, k1, Bn);
    PH_SYNC
#pragma unroll
    for (int m = 0; m < 4; ++m)
#pragma unroll
      for (int n = 0; n < 2; ++n)
#pragma unroll
        for (int ks = 0; ks < 2; ++ks)
          acc[4 + m][n] = __builtin_amdgcn_mfma_f32_16x16x32_bf16(
              af[m][ks], bfL[n][ks], acc[4 + m][n], 0, 0, 0);
    PH_END

    // ---- phase 4: quadrant (mih=1, njh=1) ----
    if (st) stage(Ag, lda, 1, k1, An);
    PH_SYNC
#pragma unroll
    for (int m = 0; m < 4; ++m)
#pragma unroll
      for (int n = 0; n < 2; ++n)
#pragma unroll
        for (int ks = 0; ks < 2; ++ks)
          acc[4 + m][2 + n] = __builtin_amdgcn_mfma_f32_16x16x32_bf16(
              af[m][ks], bfH[n][ks], acc[4 + m][2 + n], 0, 0, 0);
    PH_END
  }

  // Epilogue. C/D frag layout: col = l15, row = g*4 + r (m89-verified).
  const int rbase = bx * 256;
  const int cbase = by * 256;

  if (STORE == ST_F32) {
    float* C = (float*)Cout + (long)bz * cS;
#pragma unroll
    for (int mi = 0; mi < 8; ++mi)
#pragma unroll
      for (int nj = 0; nj < 4; ++nj)
#pragma unroll
        for (int r = 0; r < 4; ++r) {
          int row = rbase + ((mi * 2 + wm) << 4) + (g << 2) + r;
          int col = cbase + ((nj * 4 + wn) << 4) + l15;
          C[(long)row * ldc + col] = acc[mi][nj][r];
        }
  } else if (STORE == ST_BF16) {
    unsigned short* C = (unsigned short*)Cout + (long)bz * cS;
#pragma unroll
    for (int mi = 0; mi < 8; ++mi)
#pragma unroll
      for (int nj = 0; nj < 4; ++nj)
#pragma unroll
        for (int r = 0; r < 4; ++r) {
          int row = rbase + ((mi * 2 + wm) << 4) + (g << 2) + r;
          int col = cbase + ((nj * 4 + wn) << 4) + l15;
          C[(long)row * ldc + col] = f2bf(acc[mi][nj][r]);
        }
  } else {  // ST_QKV: by 0,1 -> Q; 2,3 -> K; 4,5 -> V^T [b][d][s]
    const int widx = by >> 1;
    unsigned short* dst = (widx == 0) ? qd : ((widx == 1) ? kd : vd);
#pragma unroll
    for (int mi = 0; mi < 8; ++mi)
#pragma unroll
      for (int nj = 0; nj < 4; ++nj)
#pragma unroll
        for (int r = 0; r < 4; ++r) {
          int row = rbase + ((mi * 2 + wm) << 4) + (g << 2) + r;  // b*1024+s
          int col = ((by & 1) << 8) + ((nj * 4 + wn) << 4) + l15;
          unsigned short v = f2bf(acc[mi][nj][r]);
          if (widx < 2)
            dst[(long)row * 512 + col] = v;
          else
            dst[(long)(row >> 10) * 524288 + (long)col * 1024 + (row & 1023)] =
                v;
        }
  }
}

// In-place row softmax over 32768 rows of 1024 bf16. One wave per row.
__global__ __launch_bounds__(256) void softmax_rows(
    unsigned short* __restrict__ S) {
  const long row = (long)blockIdx.x * 4 + (threadIdx.x >> 6);
  const int lane = threadIdx.x & 63;
  unsigned short* p = S + row * 1024 + lane * 16;
  uint4 u0 = *(const uint4*)p;
  uint4 u1 = *(const uint4*)(p + 8);
  unsigned int us[8] = {u0.x, u0.y, u0.z, u0.w, u1.x, u1.y, u1.z, u1.w};
  float v[16];
#pragma unroll
  for (int j = 0; j < 8; ++j) {
    v[2 * j] = __uint_as_float(us[j] << 16);
    v[2 * j + 1] = __uint_as_float(us[j] & 0xffff0000u);
  }
  float m = v[0];
#pragma unroll
  for (int i = 1; i < 16; ++i) m = fmaxf(m, v[i]);
#pragma unroll
  for (int off = 32; off >= 1; off >>= 1) m = fmaxf(m, __shfl_xor(m, off, 64));
  float s = 0.0f;
#pragma unroll
  for (int i = 0; i < 16; ++i) {
    v[i] = __expf(v[i] - m);
    s += v[i];
  }
#pragma unroll
  for (int off = 32; off >= 1; off >>= 1) s += __shfl_xor(s, off, 64);
  const float inv = 1.0f / s;
#pragma unroll
  for (int j = 0; j < 8; ++j) {
    unsigned int lo = f2bf(v[2 * j] * inv);
    unsigned int hi = f2bf(v[2 * j + 1] * inv);
    us[j] = lo | (hi << 16);
  }
  uint4 o0 = {us[0], us[1], us[2], us[3]};
  uint4 o1 = {us[4], us[5], us[6], us[7]};
  *(uint4*)p = o0;
  *(uint4*)(p + 8) = o1;
}

// Convert x and the three 512x512 weights to bf16 (Wq pre-scaled by 1/sqrt(512)).
__global__ __launch_bounds__(256) void convert_in(
    const float* __restrict__ x, const float* __restrict__ wq,
    const float* __restrict__ wk, const float* __restrict__ wv,
    unsigned short* __restrict__ xb, unsigned short* __restrict__ wb) {
  const long i = (long)blockIdx.x * 256 + threadIdx.x;
  const long NX4 = 16777216 / 4;
  const float* src;
  unsigned short* dst;
  long off;
  float sc = 1.0f;
  if (i < NX4) {
    src = x;
    dst = xb;
    off = i;
  } else {
    long r = i - NX4;
    int w = (int)(r >> 16);
    off = r & 65535;
    src = (w == 0) ? wq : (w == 1) ? wk : wv;
    dst = wb + (long)w * 262144;
    if (w == 0) sc = 0.044194173824159216f;  // 1/sqrt(512)
  }
  float4 f = ((const float4*)src)[off];
  ushort4 o;
  o.x = f2bf(f.x * sc);
  o.y = f2bf(f.y * sc);
  o.z = f2bf(f.z * sc);
  o.w = f2bf(f.w * sc);
  ((ushort4*)dst)[off] = o;
}

extern "C" void kernel_launch(void* const* d_in, const int* in_sizes, int n_in,
                              void* d_out, int out_size, void* d_ws,
                              size_t ws_size, hipStream_t stream) {
  const float* x = (const float*)d_in[0];
  const float* wq = (const float*)d_in[1];
  const float* wk = (const float*)d_in[2];
  const float* wv = (const float*)d_in[3];
  float* out = (float*)d_out;

  unsigned short* xb = (unsigned short*)d_ws;  // 16777216
  unsigned short* wb = xb + 16777216;          // 3*262144 (wq_s|wk|wv)
  unsigned short* qb = wb + 786432;            // 16777216
  unsigned short* kb = qb + 16777216;          // 16777216
  unsigned short* vtb = kb + 16777216;         // 16777216 (V^T [b][d][s])
  unsigned short* sb = vtb + 16777216;         // 33554432 (S -> P in place)

  convert_in<<<17152, 256, 0, stream>>>(x, wq, wk, wv, xb, wb);

  // QKV: M=32768, N=1536, K=512 (768 blocks, XCD-supertiled)
  gemm8p<ST_QKV, 0><<<768, 512, 0, stream>>>(xb, wb, nullptr, 512, 512, 512, 0,
                                             0L, 0L, 0L, qb, kb, vtb);

  // S = Q K^T per batch: M=N=1024, K=512 (512 blocks, batch-per-XCD)
  gemm8p<ST_BF16, 1><<<512, 512, 0, stream>>>(qb, kb, sb, 512, 512, 512, 1024,
                                              524288L, 524288L, 1048576L,
                                              nullptr, nullptr, nullptr);

  softmax_rows<<<8192, 256, 0, stream>>>(sb);

  // out = P V: M=1024, N=512, K=1024 (256 blocks, batch-per-XCD)
  gemm8p<ST_F32, 2><<<256, 512, 0, stream>>>(sb, vtb, out, 1024, 1024, 1024,
                                             512, 1048576L, 524288L, 524288L,
                                             nullptr, nullptr, nullptr);
}